// Round 13
// baseline (185.132 us; speedup 1.0000x reference)
//
#include <hip/hip_runtime.h>

#define S 2048
#define D 768
#define NH 12
#define HD 64
#define TD (3 * D)
#define GBK 64

typedef __bf16 bf16_t;
typedef __bf16 v8bf __attribute__((ext_vector_type(8)));
typedef __bf16 v4bf __attribute__((ext_vector_type(4)));
typedef float v4f __attribute__((ext_vector_type(4)));

// ---------- reductions ----------
__device__ __forceinline__ float wave_allreduce_sum(float v) {
#pragma unroll
    for (int o = 32; o > 0; o >>= 1) v += __shfl_xor(v, o, 64);
    return v;
}

// counted vmcnt wait with literal immediates
template <int N>
__device__ __forceinline__ void wait_vmcnt() {
    if constexpr (N == 0) asm volatile("s_waitcnt vmcnt(0)" ::: "memory");
    else if constexpr (N == 1) asm volatile("s_waitcnt vmcnt(1)" ::: "memory");
    else if constexpr (N == 2) asm volatile("s_waitcnt vmcnt(2)" ::: "memory");
    else if constexpr (N == 3) asm volatile("s_waitcnt vmcnt(3)" ::: "memory");
    else if constexpr (N == 4) asm volatile("s_waitcnt vmcnt(4)" ::: "memory");
    else if constexpr (N == 5) asm volatile("s_waitcnt vmcnt(5)" ::: "memory");
    else if constexpr (N == 6) asm volatile("s_waitcnt vmcnt(6)" ::: "memory");
    else if constexpr (N == 7) asm volatile("s_waitcnt vmcnt(7)" ::: "memory");
    else asm volatile("s_waitcnt vmcnt(8)" ::: "memory");
}

// ---------- fused: add+LN (wave-per-row) | weight cvt (4 units/thread) | adj compaction ----------
#define NW0 (TD * D / 4)
#define NW1 (D * D / 4)
#define NW2 ((D / 2) * D / 4)
#define NW3 (D * (D / 2) / 4)
#define NWALL (NW0 + NW1 + NW2 + NW3)
#define ADDLN_B (S / 4)          // 512 blocks, wave-per-row
#define CVT_B 720                // 720 blocks x 1024 units
#define ADJB_B (S / 4)           // 512 blocks, wave-per-row

__global__ __launch_bounds__(256) void addln_cvt(const float* __restrict__ A, const float* __restrict__ Bv,
                                                 const float* __restrict__ g, const float* __restrict__ be,
                                                 bf16_t* __restrict__ out,
                                                 const float* __restrict__ s0, const float* __restrict__ s1,
                                                 const float* __restrict__ s2, const float* __restrict__ s3,
                                                 bf16_t* __restrict__ d0, bf16_t* __restrict__ d1,
                                                 bf16_t* __restrict__ d2, bf16_t* __restrict__ d3,
                                                 const int* __restrict__ adj,
                                                 int* __restrict__ nbr_idx, int* __restrict__ nbr_cnt) {
    const int blk = blockIdx.x, t = threadIdx.x;
    const int lane = t & 63, wave = t >> 6;

    if (blk < ADDLN_B) {
        // add + LN, one wave per row; lane owns 3 float4 chunks (12 elems); no __syncthreads
        const int row = blk * 4 + wave;
        const float4* a4 = (const float4*)(A + (size_t)row * D);
        const float4* b4 = (const float4*)(Bv + (size_t)row * D);
        float4 x[3];
        float s = 0.f;
#pragma unroll
        for (int i = 0; i < 3; ++i) {
            int c = lane + 64 * i;
            float4 av = a4[c], bv = b4[c];
            x[i].x = av.x + bv.x; x[i].y = av.y + bv.y;
            x[i].z = av.z + bv.z; x[i].w = av.w + bv.w;
            s += x[i].x + x[i].y + x[i].z + x[i].w;
        }
        float mean = wave_allreduce_sum(s) * (1.0f / D);
        float vs = 0.f;
#pragma unroll
        for (int i = 0; i < 3; ++i) {
            float dx = x[i].x - mean, dy = x[i].y - mean, dz = x[i].z - mean, dw = x[i].w - mean;
            vs += dx * dx + dy * dy + dz * dz + dw * dw;
        }
        float rstd = rsqrtf(wave_allreduce_sum(vs) * (1.0f / D) + 1e-5f);
#pragma unroll
        for (int i = 0; i < 3; ++i) {
            int c = lane + 64 * i;
            float4 gv = ((const float4*)g)[c];
            float4 bev = ((const float4*)be)[c];
            v4bf o = {(bf16_t)((x[i].x - mean) * rstd * gv.x + bev.x),
                      (bf16_t)((x[i].y - mean) * rstd * gv.y + bev.y),
                      (bf16_t)((x[i].z - mean) * rstd * gv.z + bev.z),
                      (bf16_t)((x[i].w - mean) * rstd * gv.w + bev.w)};
            *(v4bf*)(out + (size_t)row * D + c * 4) = o;
        }
        return;
    }
    if (blk < ADDLN_B + CVT_B) {
        // weight conversion: 4 float4 units per thread
        int base = (blk - ADDLN_B) * 1024 + t;
#pragma unroll
        for (int r = 0; r < 4; ++r) {
            int i = base + 256 * r;
            if (i >= NWALL) break;
            const float* sp; bf16_t* dp;
            if (i < NW0) { sp = s0; dp = d0; }
            else if (i < NW0 + NW1) { sp = s1; dp = d1; i -= NW0; }
            else if (i < NW0 + NW1 + NW2) { sp = s2; dp = d2; i -= NW0 + NW1; }
            else { sp = s3; dp = d3; i -= NW0 + NW1 + NW2; }
            float4 v = ((const float4*)sp)[i];
            v4bf o = {(bf16_t)v.x, (bf16_t)v.y, (bf16_t)v.z, (bf16_t)v.w};
            *(v4bf*)(dp + (size_t)i * 4) = o;
        }
        return;
    }
    // adjacency compaction: wave-per-row ballot scan (deterministic; R3-verified)
    {
        const int row = (blk - ADDLN_B - CVT_B) * 4 + wave;
        int cnt = 0;
        const int4* arow = (const int4*)(adj + (size_t)row * S);
        const unsigned long long lt = (1ull << lane) - 1;
        int* dst = nbr_idx + (size_t)row * 128;
#pragma unroll
        for (int p = 0; p < 8; ++p) {
            int4 v = arow[lane + 64 * p];
            int base = (lane + 64 * p) * 4;
            int f[4] = {v.x, v.y, v.z, v.w};
#pragma unroll
            for (int c = 0; c < 4; ++c) {
                unsigned long long m = __ballot(f[c] != 0);
                if (f[c]) {
                    int k = cnt + (int)__popcll(m & lt);
                    if (k < 128) dst[k] = base + c;
                }
                cnt += (int)__popcll(m);
            }
        }
        if (lane == 0) nbr_cnt[row] = (cnt < 128) ? cnt : 128;
    }
}

// ---------- single-input LayerNorm: wave-per-row, 4 rows/block, no __syncthreads ----------
template <typename TO>
__global__ __launch_bounds__(256) void ln_only(const bf16_t* __restrict__ X,
                                               const float* __restrict__ g, const float* __restrict__ be,
                                               TO* __restrict__ out) {
    const int lane = threadIdx.x & 63, wave = threadIdx.x >> 6;
    const int row = blockIdx.x * 4 + wave;
    const bf16_t* a = X + (size_t)row * D;

    // lane owns v8bf chunk `lane`; lanes 0..31 additionally own chunk lane+64 (96 chunks total)
    float xa[8], xb[8];
    float s = 0.f;
    v8bf ya = *(const v8bf*)(a + lane * 8);
#pragma unroll
    for (int e = 0; e < 8; ++e) { xa[e] = (float)ya[e]; s += xa[e]; }
    if (lane < 32) {
        v8bf yb = *(const v8bf*)(a + (lane + 64) * 8);
#pragma unroll
        for (int e = 0; e < 8; ++e) { xb[e] = (float)yb[e]; s += xb[e]; }
    }
    float mean = wave_allreduce_sum(s) * (1.0f / D);
    float vs = 0.f;
#pragma unroll
    for (int e = 0; e < 8; ++e) { float d2 = xa[e] - mean; vs += d2 * d2; }
    if (lane < 32) {
#pragma unroll
        for (int e = 0; e < 8; ++e) { float d2 = xb[e] - mean; vs += d2 * d2; }
    }
    float rstd = rsqrtf(wave_allreduce_sum(vs) * (1.0f / D) + 1e-5f);

    {
        float4 g0 = *(const float4*)(g + lane * 8), g1 = *(const float4*)(g + lane * 8 + 4);
        float4 b0 = *(const float4*)(be + lane * 8), b1 = *(const float4*)(be + lane * 8 + 4);
        float r0[8] = {g0.x, g0.y, g0.z, g0.w, g1.x, g1.y, g1.z, g1.w};
        float r1[8] = {b0.x, b0.y, b0.z, b0.w, b1.x, b1.y, b1.z, b1.w};
        if constexpr (sizeof(TO) == 2) {
            v8bf o;
#pragma unroll
            for (int e = 0; e < 8; ++e) o[e] = (bf16_t)((xa[e] - mean) * rstd * r0[e] + r1[e]);
            *(v8bf*)((bf16_t*)out + (size_t)row * D + lane * 8) = o;
        } else {
            float4 o0, o1;
            o0.x = (xa[0] - mean) * rstd * r0[0] + r1[0]; o0.y = (xa[1] - mean) * rstd * r0[1] + r1[1];
            o0.z = (xa[2] - mean) * rstd * r0[2] + r1[2]; o0.w = (xa[3] - mean) * rstd * r0[3] + r1[3];
            o1.x = (xa[4] - mean) * rstd * r0[4] + r1[4]; o1.y = (xa[5] - mean) * rstd * r0[5] + r1[5];
            o1.z = (xa[6] - mean) * rstd * r0[6] + r1[6]; o1.w = (xa[7] - mean) * rstd * r0[7] + r1[7];
            *(float4*)((float*)out + (size_t)row * D + lane * 8) = o0;
            *(float4*)((float*)out + (size_t)row * D + lane * 8 + 4) = o1;
        }
    }
    if (lane < 32) {
        const int c0 = (lane + 64) * 8;
        float4 g0 = *(const float4*)(g + c0), g1 = *(const float4*)(g + c0 + 4);
        float4 b0 = *(const float4*)(be + c0), b1 = *(const float4*)(be + c0 + 4);
        float r0[8] = {g0.x, g0.y, g0.z, g0.w, g1.x, g1.y, g1.z, g1.w};
        float r1[8] = {b0.x, b0.y, b0.z, b0.w, b1.x, b1.y, b1.z, b1.w};
        if constexpr (sizeof(TO) == 2) {
            v8bf o;
#pragma unroll
            for (int e = 0; e < 8; ++e) o[e] = (bf16_t)((xb[e] - mean) * rstd * r0[e] + r1[e]);
            *(v8bf*)((bf16_t*)out + (size_t)row * D + c0) = o;
        } else {
            float4 o0, o1;
            o0.x = (xb[0] - mean) * rstd * r0[0] + r1[0]; o0.y = (xb[1] - mean) * rstd * r0[1] + r1[1];
            o0.z = (xb[2] - mean) * rstd * r0[2] + r1[2]; o0.w = (xb[3] - mean) * rstd * r0[3] + r1[3];
            o1.x = (xb[4] - mean) * rstd * r0[4] + r1[4]; o1.y = (xb[5] - mean) * rstd * r0[5] + r1[5];
            o1.z = (xb[6] - mean) * rstd * r0[6] + r1[6]; o1.w = (xb[7] - mean) * rstd * r0[7] + r1[7];
            *(float4*)((float*)out + (size_t)row * D + c0) = o0;
            *(float4*)((float*)out + (size_t)row * D + c0 + 4) = o1;
        }
    }
}

// ---------- MFMA GEMM (R1-proven dbuf + counted vmcnt) ----------
template <int TM, int TN, int RELU, bool RESID>
__global__ __launch_bounds__(256) void gemm_mfma(const bf16_t* __restrict__ A, const bf16_t* __restrict__ B,
                                                 const float* __restrict__ bias,
                                                 const bf16_t* __restrict__ Rsd, bf16_t* __restrict__ C,
                                                 int M, int N, int K) {
    constexpr int CA = TM * 8;
    constexpr int CHUNKS = (TM + TN) * 8;
    constexpr int P = CHUNKS / 256;
    static_assert(CHUNKS % 256 == 0, "chunk passes must be exact");
    constexpr int MI = TM / 32, NI = TN / 32;
    constexpr int BUFE = (TM + TN) * GBK;
    __shared__ bf16_t smem[2 * BUFE];
    const int t = threadIdx.x;
    const int lane = t & 63, wave = t >> 6;
    const int wr = (wave >> 1) * (TM / 2), wc = (wave & 1) * (TN / 2);
    const int m0 = blockIdx.y * TM, n0 = blockIdx.x * TN;
    const int lm = lane & 15, q = lane >> 4;

    const bf16_t* gp[P];
    int loff[P];
#pragma unroll
    for (int p = 0; p < P; ++p) {
        int c = t + 256 * p;
        if (c < CA) {
            int slab = c / (TM * 4), r4 = c % (TM * 4);
            gp[p] = A + (size_t)(m0 + (r4 >> 2)) * K + slab * 32 + (r4 & 3) * 8;
            loff[p] = slab * (TM * 32) + r4 * 8;
        } else {
            int cc = c - CA;
            int slab = cc / (TN * 4), r4 = cc % (TN * 4);
            gp[p] = B + (size_t)(n0 + (r4 >> 2)) * K + slab * 32 + (r4 & 3) * 8;
            loff[p] = TM * GBK + slab * (TN * 32) + r4 * 8;
        }
    }

    v4f acc[MI][NI] = {};

    auto stage = [&](int buf, int k0) {
#pragma unroll
        for (int p = 0; p < P; ++p)
            __builtin_amdgcn_global_load_lds(
                (const __attribute__((address_space(1))) void*)(gp[p] + k0),
                (__attribute__((address_space(3))) void*)(smem + buf * BUFE + loff[p]), 16, 0, 0);
    };

    stage(0, 0);
    int cur = 0;
    for (int k0 = 0; k0 < K; k0 += GBK) {
        if (k0 + GBK < K) {
            stage(cur ^ 1, k0 + GBK);
            __builtin_amdgcn_sched_barrier(0);
            wait_vmcnt<P>();
        } else {
            __builtin_amdgcn_sched_barrier(0);
            wait_vmcnt<0>();
        }
        __builtin_amdgcn_s_barrier();
        __builtin_amdgcn_sched_barrier(0);

        const bf16_t* As = smem + cur * BUFE;
        const bf16_t* Bs = As + TM * GBK;
        v8bf af[2][MI], bfr[2][NI];
#pragma unroll
        for (int s = 0; s < 2; ++s) {
#pragma unroll
            for (int i = 0; i < MI; ++i)
                af[s][i] = *(const v8bf*)(As + s * (TM * 32) + (wr + i * 16 + lm) * 32 + q * 8);
#pragma unroll
            for (int j = 0; j < NI; ++j)
                bfr[s][j] = *(const v8bf*)(Bs + s * (TN * 32) + (wc + j * 16 + lm) * 32 + q * 8);
        }
#pragma unroll
        for (int s = 0; s < 2; ++s)
#pragma unroll
            for (int i = 0; i < MI; ++i)
#pragma unroll
                for (int j = 0; j < NI; ++j)
                    acc[i][j] = __builtin_amdgcn_mfma_f32_16x16x32_bf16(af[s][i], bfr[s][j], acc[i][j], 0, 0, 0);
        __builtin_amdgcn_sched_barrier(0);
        __builtin_amdgcn_s_barrier();
        cur ^= 1;
    }

    // D mapping (verified m89/m91): row = quad*4 + reg, col = lane&15
#pragma unroll
    for (int i = 0; i < MI; ++i)
#pragma unroll
        for (int j = 0; j < NI; ++j) {
            int col = n0 + wc + j * 16 + lm;
            float bs = bias[col];
#pragma unroll
            for (int r = 0; r < 4; ++r) {
                int row = m0 + wr + i * 16 + q * 4 + r;
                float v = acc[i][j][r] + bs;
                if (RELU) v = fmaxf(v, 0.f);
                if (RESID) v += (float)Rsd[(size_t)row * N + col];
                C[(size_t)row * N + col] = (bf16_t)v;
            }
        }
}

// ---------- sparse attention: wave-independent (single barrier) ----------
// Each wave owns heads {wave, wave+4, wave+8} through scores -> softmax -> PV.
// s_p rows are disjoint per wave; s_q/s_idx read-only after the one barrier.
// Per-(h,i) math identical to the R7-proven kernel -> bitwise-identical output.
__global__ __launch_bounds__(256) void attn_sparse(const bf16_t* __restrict__ qkv,
                                                   const int* __restrict__ nbr_idx,
                                                   const int* __restrict__ nbr_cnt,
                                                   bf16_t* __restrict__ O) {
    __shared__ int s_idx[128];
    __shared__ float s_q[D];
    __shared__ float s_p[NH][128];

    const int row = blockIdx.x, t = threadIdx.x;
    const int lane = t & 63, wave = t >> 6;
    const int n = nbr_cnt[row];           // >= 1 (diag forced), <= 128
    const int npad = (n + 7) & ~7;        // pad to x8; pads get p=0 (exact no-op)

    if (t < 128) s_idx[t] = (t < n) ? nbr_idx[(size_t)row * 128 + t] : row;
    for (int c = t; c < D; c += 256) s_q[c] = (float)qkv[(size_t)row * TD + c];
    __syncthreads();  // ONLY block-wide barrier

    // scores: wave-local mapping over this wave's 3 heads
    for (int it = lane; it < 3 * npad; it += 64) {
        int hh = it / npad, i = it - hh * npad;
        int h = wave + hh * 4;
        if (i < n) {
            int j = s_idx[i];
            const bf16_t* kp = qkv + (size_t)j * TD + D + h * HD;
            const float* qp = s_q + h * HD;
            float dot = 0.f;
#pragma unroll
            for (int c = 0; c < HD; c += 8) {
                v8bf kv = *(const v8bf*)(kp + c);
#pragma unroll
                for (int e = 0; e < 8; ++e) dot += qp[c + e] * (float)kv[e];
            }
            s_p[h][i] = dot * 0.125f;  // 1/sqrt(64)
        } else {
            s_p[h][i] = 0.f;
        }
    }
    // no barrier: s_p rows {wave, wave+4, wave+8} written and read by this wave only

    // softmax: this wave's 3 heads (shuffle butterflies)
    for (int h = wave; h < NH; h += 4) {
        float v0 = (lane < n) ? s_p[h][lane] : -1e30f;
        float v1 = (lane + 64 < n) ? s_p[h][lane + 64] : -1e30f;
        float m = fmaxf(v0, v1);
#pragma unroll
        for (int o = 32; o > 0; o >>= 1) m = fmaxf(m, __shfl_xor(m, o, 64));
        float p0 = (lane < n) ? __expf(v0 - m) : 0.f;
        float p1 = (lane + 64 < n) ? __expf(v1 - m) : 0.f;
        float sm = p0 + p1;
#pragma unroll
        for (int o = 32; o > 0; o >>= 1) sm += __shfl_xor(sm, o, 64);
        float inv = 1.f / sm;
        if (lane < n) s_p[h][lane] = p0 * inv;
        if (lane + 64 < n) s_p[h][lane + 64] = p1 * inv;
    }
    // no barrier: same-wave s_p dependency only

    // PV: lane owns elem `lane` of heads {wave, wave+4, wave+8}
    const int h0 = wave, e = lane;
    const bf16_t* vbase = qkv + 2 * D + h0 * HD + e;
    float a0 = 0.f, a1 = 0.f, a2 = 0.f;
    for (int i = 0; i < npad; i += 8) {
        float v0[8], v1[8], v2[8], p0[8], p1[8], p2[8];
#pragma unroll
        for (int k = 0; k < 8; ++k) {
            const bf16_t* vp = vbase + (size_t)s_idx[i + k] * TD;
            v0[k] = (float)vp[0];
            v1[k] = (float)vp[256];
            v2[k] = (float)vp[512];
            p0[k] = s_p[h0][i + k];
            p1[k] = s_p[h0 + 4][i + k];
            p2[k] = s_p[h0 + 8][i + k];
        }
#pragma unroll
        for (int k = 0; k < 8; ++k) {
            a0 += p0[k] * v0[k];
            a1 += p1[k] * v1[k];
            a2 += p2[k] * v2[k];
        }
    }
    O[(size_t)row * D + h0 * HD + e] = (bf16_t)a0;
    O[(size_t)row * D + (h0 + 4) * HD + e] = (bf16_t)a1;
    O[(size_t)row * D + (h0 + 8) * HD + e] = (bf16_t)a2;
}

// ---------- launch ----------
extern "C" void kernel_launch(void* const* d_in, const int* in_sizes, int n_in,
                              void* d_out, int out_size, void* d_ws, size_t ws_size,
                              hipStream_t stream) {
    const float* exp_e = (const float*)d_in[0];
    const float* pert  = (const float*)d_in[1];
    const float* w_in  = (const float*)d_in[2];
    const float* b_in  = (const float*)d_in[3];
    const float* w_out = (const float*)d_in[4];
    const float* b_out = (const float*)d_in[5];
    const float* g0  = (const float*)d_in[6];
    const float* be0 = (const float*)d_in[7];
    const float* g1  = (const float*)d_in[8];
    const float* be1 = (const float*)d_in[9];
    const float* g2  = (const float*)d_in[10];
    const float* be2 = (const float*)d_in[11];
    const float* w1  = (const float*)d_in[12];
    const float* b1  = (const float*)d_in[13];
    const float* w2  = (const float*)d_in[14];
    const float* b2  = (const float*)d_in[15];
    const int*   adj = (const int*)d_in[16];
    float* out = (float*)d_out;

    const size_t SD = (size_t)S * D;
    bf16_t* wb_in  = (bf16_t*)d_ws;               // [2304*768]
    bf16_t* wb_out = wb_in + (size_t)TD * D;      // [768*768]
    bf16_t* wb_1   = wb_out + (size_t)D * D;      // [384*768]
    bf16_t* wb_2   = wb_1 + (size_t)(D / 2) * D;  // [768*384]
    bf16_t* x_in   = wb_2 + (size_t)D * (D / 2);  // [S*D]
    bf16_t* qkv    = x_in + SD;                   // [S*3D]
    bf16_t* attn_o = qkv + 3 * SD;                // [S*D]
    bf16_t* y1     = attn_o + SD;                 // [S*D] pre-LN1
    bf16_t* x1     = y1 + SD;                     // [S*D] ln1 out
    bf16_t* ffh    = x1 + SD;                     // [S*D/2]
    bf16_t* y2     = ffh + SD / 2;                // [S*D] pre-LN2
    int* nbr_idx   = (int*)(y2 + SD);             // [S*128]
    int* nbr_cnt   = nbr_idx + (size_t)S * 128;   // [S]

    addln_cvt<<<ADDLN_B + CVT_B + ADJB_B, 256, 0, stream>>>(exp_e, pert, g0, be0, x_in,
                                                            w_in, w_out, w1, w2, wb_in, wb_out, wb_1, wb_2,
                                                            adj, nbr_idx, nbr_cnt);
    gemm_mfma<64, 128, 0, false><<<dim3(TD / 128, S / 64), 256, 0, stream>>>(x_in, wb_in, b_in, nullptr, qkv, S, TD, D);
    attn_sparse<<<S, 256, 0, stream>>>(qkv, nbr_idx, nbr_cnt, attn_o);
    gemm_mfma<64, 64, 0, true><<<dim3(D / 64, S / 64), 256, 0, stream>>>(attn_o, wb_out, b_out, x_in, y1, S, D, D);
    ln_only<bf16_t><<<S / 4, 256, 0, stream>>>(y1, g1, be1, x1);
    gemm_mfma<32, 64, 1, false><<<dim3((D / 2) / 64, S / 32), 256, 0, stream>>>(x1, wb_1, b1, nullptr, ffh, S, D / 2, D);
    gemm_mfma<64, 64, 0, true><<<dim3(D / 64, S / 64), 256, 0, stream>>>(ffh, wb_2, b2, x1, y2, S, D, D / 2);
    ln_only<float><<<S / 4, 256, 0, stream>>>(y2, g2, be2, out);
}

// Round 14
// 183.482 us; speedup vs baseline: 1.0090x; 1.0090x over previous
//
#include <hip/hip_runtime.h>

#define S 2048
#define D 768
#define NH 12
#define HD 64
#define TD (3 * D)
#define GBK 64

typedef __bf16 bf16_t;
typedef __bf16 v8bf __attribute__((ext_vector_type(8)));
typedef __bf16 v4bf __attribute__((ext_vector_type(4)));
typedef float v4f __attribute__((ext_vector_type(4)));

// ---------- reductions ----------
__device__ __forceinline__ float wave_allreduce_sum(float v) {
#pragma unroll
    for (int o = 32; o > 0; o >>= 1) v += __shfl_xor(v, o, 64);
    return v;
}

// counted vmcnt wait with literal immediates
template <int N>
__device__ __forceinline__ void wait_vmcnt() {
    if constexpr (N == 0) asm volatile("s_waitcnt vmcnt(0)" ::: "memory");
    else if constexpr (N == 1) asm volatile("s_waitcnt vmcnt(1)" ::: "memory");
    else if constexpr (N == 2) asm volatile("s_waitcnt vmcnt(2)" ::: "memory");
    else if constexpr (N == 3) asm volatile("s_waitcnt vmcnt(3)" ::: "memory");
    else if constexpr (N == 4) asm volatile("s_waitcnt vmcnt(4)" ::: "memory");
    else if constexpr (N == 5) asm volatile("s_waitcnt vmcnt(5)" ::: "memory");
    else if constexpr (N == 6) asm volatile("s_waitcnt vmcnt(6)" ::: "memory");
    else if constexpr (N == 7) asm volatile("s_waitcnt vmcnt(7)" ::: "memory");
    else asm volatile("s_waitcnt vmcnt(8)" ::: "memory");
}

// ---------- fused: add+LN (wave-per-row) | weight cvt (4 units/thread) | adj compaction ----------
#define NW0 (TD * D / 4)
#define NW1 (D * D / 4)
#define NW2 ((D / 2) * D / 4)
#define NW3 (D * (D / 2) / 4)
#define NWALL (NW0 + NW1 + NW2 + NW3)
#define ADDLN_B (S / 4)          // 512 blocks, wave-per-row
#define CVT_B 720                // 720 blocks x 1024 units
#define ADJB_B (S / 4)           // 512 blocks, wave-per-row

__global__ __launch_bounds__(256) void addln_cvt(const float* __restrict__ A, const float* __restrict__ Bv,
                                                 const float* __restrict__ g, const float* __restrict__ be,
                                                 bf16_t* __restrict__ out,
                                                 const float* __restrict__ s0, const float* __restrict__ s1,
                                                 const float* __restrict__ s2, const float* __restrict__ s3,
                                                 bf16_t* __restrict__ d0, bf16_t* __restrict__ d1,
                                                 bf16_t* __restrict__ d2, bf16_t* __restrict__ d3,
                                                 const int* __restrict__ adj,
                                                 int* __restrict__ nbr_idx, int* __restrict__ nbr_cnt) {
    const int blk = blockIdx.x, t = threadIdx.x;
    const int lane = t & 63, wave = t >> 6;

    if (blk < ADDLN_B) {
        // add + LN, one wave per row; lane owns 3 float4 chunks (12 elems); no __syncthreads
        const int row = blk * 4 + wave;
        const float4* a4 = (const float4*)(A + (size_t)row * D);
        const float4* b4 = (const float4*)(Bv + (size_t)row * D);
        float4 x[3];
        float s = 0.f;
#pragma unroll
        for (int i = 0; i < 3; ++i) {
            int c = lane + 64 * i;
            float4 av = a4[c], bv = b4[c];
            x[i].x = av.x + bv.x; x[i].y = av.y + bv.y;
            x[i].z = av.z + bv.z; x[i].w = av.w + bv.w;
            s += x[i].x + x[i].y + x[i].z + x[i].w;
        }
        float mean = wave_allreduce_sum(s) * (1.0f / D);
        float vs = 0.f;
#pragma unroll
        for (int i = 0; i < 3; ++i) {
            float dx = x[i].x - mean, dy = x[i].y - mean, dz = x[i].z - mean, dw = x[i].w - mean;
            vs += dx * dx + dy * dy + dz * dz + dw * dw;
        }
        float rstd = rsqrtf(wave_allreduce_sum(vs) * (1.0f / D) + 1e-5f);
#pragma unroll
        for (int i = 0; i < 3; ++i) {
            int c = lane + 64 * i;
            float4 gv = ((const float4*)g)[c];
            float4 bev = ((const float4*)be)[c];
            v4bf o = {(bf16_t)((x[i].x - mean) * rstd * gv.x + bev.x),
                      (bf16_t)((x[i].y - mean) * rstd * gv.y + bev.y),
                      (bf16_t)((x[i].z - mean) * rstd * gv.z + bev.z),
                      (bf16_t)((x[i].w - mean) * rstd * gv.w + bev.w)};
            *(v4bf*)(out + (size_t)row * D + c * 4) = o;
        }
        return;
    }
    if (blk < ADDLN_B + CVT_B) {
        // weight conversion: 4 float4 units per thread
        int base = (blk - ADDLN_B) * 1024 + t;
#pragma unroll
        for (int r = 0; r < 4; ++r) {
            int i = base + 256 * r;
            if (i >= NWALL) break;
            const float* sp; bf16_t* dp;
            if (i < NW0) { sp = s0; dp = d0; }
            else if (i < NW0 + NW1) { sp = s1; dp = d1; i -= NW0; }
            else if (i < NW0 + NW1 + NW2) { sp = s2; dp = d2; i -= NW0 + NW1; }
            else { sp = s3; dp = d3; i -= NW0 + NW1 + NW2; }
            float4 v = ((const float4*)sp)[i];
            v4bf o = {(bf16_t)v.x, (bf16_t)v.y, (bf16_t)v.z, (bf16_t)v.w};
            *(v4bf*)(dp + (size_t)i * 4) = o;
        }
        return;
    }
    // adjacency compaction: wave-per-row ballot scan (deterministic; R3-verified)
    {
        const int row = (blk - ADDLN_B - CVT_B) * 4 + wave;
        int cnt = 0;
        const int4* arow = (const int4*)(adj + (size_t)row * S);
        const unsigned long long lt = (1ull << lane) - 1;
        int* dst = nbr_idx + (size_t)row * 128;
#pragma unroll
        for (int p = 0; p < 8; ++p) {
            int4 v = arow[lane + 64 * p];
            int base = (lane + 64 * p) * 4;
            int f[4] = {v.x, v.y, v.z, v.w};
#pragma unroll
            for (int c = 0; c < 4; ++c) {
                unsigned long long m = __ballot(f[c] != 0);
                if (f[c]) {
                    int k = cnt + (int)__popcll(m & lt);
                    if (k < 128) dst[k] = base + c;
                }
                cnt += (int)__popcll(m);
            }
        }
        if (lane == 0) nbr_cnt[row] = (cnt < 128) ? cnt : 128;
    }
}

// ---------- single-input LayerNorm: wave-per-row, 4 rows/block, no __syncthreads ----------
template <typename TO>
__global__ __launch_bounds__(256) void ln_only(const bf16_t* __restrict__ X,
                                               const float* __restrict__ g, const float* __restrict__ be,
                                               TO* __restrict__ out) {
    const int lane = threadIdx.x & 63, wave = threadIdx.x >> 6;
    const int row = blockIdx.x * 4 + wave;
    const bf16_t* a = X + (size_t)row * D;

    // lane owns v8bf chunk `lane`; lanes 0..31 additionally own chunk lane+64 (96 chunks total)
    float xa[8], xb[8];
    float s = 0.f;
    v8bf ya = *(const v8bf*)(a + lane * 8);
#pragma unroll
    for (int e = 0; e < 8; ++e) { xa[e] = (float)ya[e]; s += xa[e]; }
    if (lane < 32) {
        v8bf yb = *(const v8bf*)(a + (lane + 64) * 8);
#pragma unroll
        for (int e = 0; e < 8; ++e) { xb[e] = (float)yb[e]; s += xb[e]; }
    }
    float mean = wave_allreduce_sum(s) * (1.0f / D);
    float vs = 0.f;
#pragma unroll
    for (int e = 0; e < 8; ++e) { float d2 = xa[e] - mean; vs += d2 * d2; }
    if (lane < 32) {
#pragma unroll
        for (int e = 0; e < 8; ++e) { float d2 = xb[e] - mean; vs += d2 * d2; }
    }
    float rstd = rsqrtf(wave_allreduce_sum(vs) * (1.0f / D) + 1e-5f);

    {
        float4 g0 = *(const float4*)(g + lane * 8), g1 = *(const float4*)(g + lane * 8 + 4);
        float4 b0 = *(const float4*)(be + lane * 8), b1 = *(const float4*)(be + lane * 8 + 4);
        float r0[8] = {g0.x, g0.y, g0.z, g0.w, g1.x, g1.y, g1.z, g1.w};
        float r1[8] = {b0.x, b0.y, b0.z, b0.w, b1.x, b1.y, b1.z, b1.w};
        if constexpr (sizeof(TO) == 2) {
            v8bf o;
#pragma unroll
            for (int e = 0; e < 8; ++e) o[e] = (bf16_t)((xa[e] - mean) * rstd * r0[e] + r1[e]);
            *(v8bf*)((bf16_t*)out + (size_t)row * D + lane * 8) = o;
        } else {
            float4 o0, o1;
            o0.x = (xa[0] - mean) * rstd * r0[0] + r1[0]; o0.y = (xa[1] - mean) * rstd * r0[1] + r1[1];
            o0.z = (xa[2] - mean) * rstd * r0[2] + r1[2]; o0.w = (xa[3] - mean) * rstd * r0[3] + r1[3];
            o1.x = (xa[4] - mean) * rstd * r0[4] + r1[4]; o1.y = (xa[5] - mean) * rstd * r0[5] + r1[5];
            o1.z = (xa[6] - mean) * rstd * r0[6] + r1[6]; o1.w = (xa[7] - mean) * rstd * r0[7] + r1[7];
            *(float4*)((float*)out + (size_t)row * D + lane * 8) = o0;
            *(float4*)((float*)out + (size_t)row * D + lane * 8 + 4) = o1;
        }
    }
    if (lane < 32) {
        const int c0 = (lane + 64) * 8;
        float4 g0 = *(const float4*)(g + c0), g1 = *(const float4*)(g + c0 + 4);
        float4 b0 = *(const float4*)(be + c0), b1 = *(const float4*)(be + c0 + 4);
        float r0[8] = {g0.x, g0.y, g0.z, g0.w, g1.x, g1.y, g1.z, g1.w};
        float r1[8] = {b0.x, b0.y, b0.z, b0.w, b1.x, b1.y, b1.z, b1.w};
        if constexpr (sizeof(TO) == 2) {
            v8bf o;
#pragma unroll
            for (int e = 0; e < 8; ++e) o[e] = (bf16_t)((xb[e] - mean) * rstd * r0[e] + r1[e]);
            *(v8bf*)((bf16_t*)out + (size_t)row * D + c0) = o;
        } else {
            float4 o0, o1;
            o0.x = (xb[0] - mean) * rstd * r0[0] + r1[0]; o0.y = (xb[1] - mean) * rstd * r0[1] + r1[1];
            o0.z = (xb[2] - mean) * rstd * r0[2] + r1[2]; o0.w = (xb[3] - mean) * rstd * r0[3] + r1[3];
            o1.x = (xb[4] - mean) * rstd * r0[4] + r1[4]; o1.y = (xb[5] - mean) * rstd * r0[5] + r1[5];
            o1.z = (xb[6] - mean) * rstd * r0[6] + r1[6]; o1.w = (xb[7] - mean) * rstd * r0[7] + r1[7];
            *(float4*)((float*)out + (size_t)row * D + c0) = o0;
            *(float4*)((float*)out + (size_t)row * D + c0 + 4) = o1;
        }
    }
}

// ---------- MFMA GEMM (R1-proven dbuf + counted vmcnt) ----------
template <int TM, int TN, int RELU, bool RESID>
__global__ __launch_bounds__(256) void gemm_mfma(const bf16_t* __restrict__ A, const bf16_t* __restrict__ B,
                                                 const float* __restrict__ bias,
                                                 const bf16_t* __restrict__ Rsd, bf16_t* __restrict__ C,
                                                 int M, int N, int K) {
    constexpr int CA = TM * 8;
    constexpr int CHUNKS = (TM + TN) * 8;
    constexpr int P = CHUNKS / 256;
    static_assert(CHUNKS % 256 == 0, "chunk passes must be exact");
    constexpr int MI = TM / 32, NI = TN / 32;
    constexpr int BUFE = (TM + TN) * GBK;
    __shared__ bf16_t smem[2 * BUFE];
    const int t = threadIdx.x;
    const int lane = t & 63, wave = t >> 6;
    const int wr = (wave >> 1) * (TM / 2), wc = (wave & 1) * (TN / 2);
    const int m0 = blockIdx.y * TM, n0 = blockIdx.x * TN;
    const int lm = lane & 15, q = lane >> 4;

    const bf16_t* gp[P];
    int loff[P];
#pragma unroll
    for (int p = 0; p < P; ++p) {
        int c = t + 256 * p;
        if (c < CA) {
            int slab = c / (TM * 4), r4 = c % (TM * 4);
            gp[p] = A + (size_t)(m0 + (r4 >> 2)) * K + slab * 32 + (r4 & 3) * 8;
            loff[p] = slab * (TM * 32) + r4 * 8;
        } else {
            int cc = c - CA;
            int slab = cc / (TN * 4), r4 = cc % (TN * 4);
            gp[p] = B + (size_t)(n0 + (r4 >> 2)) * K + slab * 32 + (r4 & 3) * 8;
            loff[p] = TM * GBK + slab * (TN * 32) + r4 * 8;
        }
    }

    v4f acc[MI][NI] = {};

    auto stage = [&](int buf, int k0) {
#pragma unroll
        for (int p = 0; p < P; ++p)
            __builtin_amdgcn_global_load_lds(
                (const __attribute__((address_space(1))) void*)(gp[p] + k0),
                (__attribute__((address_space(3))) void*)(smem + buf * BUFE + loff[p]), 16, 0, 0);
    };

    stage(0, 0);
    int cur = 0;
    for (int k0 = 0; k0 < K; k0 += GBK) {
        if (k0 + GBK < K) {
            stage(cur ^ 1, k0 + GBK);
            __builtin_amdgcn_sched_barrier(0);
            wait_vmcnt<P>();
        } else {
            __builtin_amdgcn_sched_barrier(0);
            wait_vmcnt<0>();
        }
        __builtin_amdgcn_s_barrier();
        __builtin_amdgcn_sched_barrier(0);

        const bf16_t* As = smem + cur * BUFE;
        const bf16_t* Bs = As + TM * GBK;
        v8bf af[2][MI], bfr[2][NI];
#pragma unroll
        for (int s = 0; s < 2; ++s) {
#pragma unroll
            for (int i = 0; i < MI; ++i)
                af[s][i] = *(const v8bf*)(As + s * (TM * 32) + (wr + i * 16 + lm) * 32 + q * 8);
#pragma unroll
            for (int j = 0; j < NI; ++j)
                bfr[s][j] = *(const v8bf*)(Bs + s * (TN * 32) + (wc + j * 16 + lm) * 32 + q * 8);
        }
#pragma unroll
        for (int s = 0; s < 2; ++s)
#pragma unroll
            for (int i = 0; i < MI; ++i)
#pragma unroll
                for (int j = 0; j < NI; ++j)
                    acc[i][j] = __builtin_amdgcn_mfma_f32_16x16x32_bf16(af[s][i], bfr[s][j], acc[i][j], 0, 0, 0);
        __builtin_amdgcn_sched_barrier(0);
        __builtin_amdgcn_s_barrier();
        cur ^= 1;
    }

    // D mapping (verified m89/m91): row = quad*4 + reg, col = lane&15
#pragma unroll
    for (int i = 0; i < MI; ++i)
#pragma unroll
        for (int j = 0; j < NI; ++j) {
            int col = n0 + wc + j * 16 + lm;
            float bs = bias[col];
#pragma unroll
            for (int r = 0; r < 4; ++r) {
                int row = m0 + wr + i * 16 + q * 4 + r;
                float v = acc[i][j][r] + bs;
                if (RELU) v = fmaxf(v, 0.f);
                if (RESID) v += (float)Rsd[(size_t)row * N + col];
                C[(size_t)row * N + col] = (bf16_t)v;
            }
        }
}

// ---------- sparse attention (R7-proven: thread-per-dot scores + fused PV) ----------
__global__ __launch_bounds__(256) void attn_sparse(const bf16_t* __restrict__ qkv,
                                                   const int* __restrict__ nbr_idx,
                                                   const int* __restrict__ nbr_cnt,
                                                   bf16_t* __restrict__ O) {
    __shared__ int s_idx[128];
    __shared__ float s_q[D];
    __shared__ float s_p[NH][128];

    const int row = blockIdx.x, t = threadIdx.x;
    const int lane = t & 63, wave = t >> 6;
    const int n = nbr_cnt[row];           // >= 1 (diag forced), <= 128
    const int npad = (n + 7) & ~7;        // pad to x8; pads get p=0 (exact no-op)

    if (t < 128) s_idx[t] = (t < n) ? nbr_idx[(size_t)row * 128 + t] : row;
    for (int c = t; c < D; c += 256) s_q[c] = (float)qkv[(size_t)row * TD + c];
    __syncthreads();

    // scores over padded range; pad entries written 0 and untouched by softmax
    for (int it = t; it < npad * NH; it += 256) {
        int h = it / npad, i = it - h * npad;
        if (i < n) {
            int j = s_idx[i];
            const bf16_t* kp = qkv + (size_t)j * TD + D + h * HD;
            const float* qp = s_q + h * HD;
            float dot = 0.f;
#pragma unroll
            for (int c = 0; c < HD; c += 8) {
                v8bf kv = *(const v8bf*)(kp + c);
#pragma unroll
                for (int e = 0; e < 8; ++e) dot += qp[c + e] * (float)kv[e];
            }
            s_p[h][i] = dot * 0.125f;  // 1/sqrt(64)
        } else {
            s_p[h][i] = 0.f;
        }
    }
    __syncthreads();

    // softmax: 3 heads per wave (reads/writes only i < n)
    for (int h = wave; h < NH; h += 4) {
        float v0 = (lane < n) ? s_p[h][lane] : -1e30f;
        float v1 = (lane + 64 < n) ? s_p[h][lane + 64] : -1e30f;
        float m = fmaxf(v0, v1);
#pragma unroll
        for (int o = 32; o > 0; o >>= 1) m = fmaxf(m, __shfl_xor(m, o, 64));
        float p0 = (lane < n) ? __expf(v0 - m) : 0.f;
        float p1 = (lane + 64 < n) ? __expf(v1 - m) : 0.f;
        float sm = p0 + p1;
#pragma unroll
        for (int o = 32; o > 0; o >>= 1) sm += __shfl_xor(sm, o, 64);
        float inv = 1.f / sm;
        if (lane < n) s_p[h][lane] = p0 * inv;
        if (lane + 64 < n) s_p[h][lane + 64] = p1 * inv;
    }
    __syncthreads();

    // PV: thread owns outputs {t, t+256, t+512} = heads {h0, h0+4, h0+8}, elem e.
    const int h0 = t >> 6, e = t & 63;
    const bf16_t* vbase = qkv + 2 * D + h0 * HD + e;
    float a0 = 0.f, a1 = 0.f, a2 = 0.f;
    for (int i = 0; i < npad; i += 8) {
        float v0[8], v1[8], v2[8], p0[8], p1[8], p2[8];
#pragma unroll
        for (int k = 0; k < 8; ++k) {
            const bf16_t* vp = vbase + (size_t)s_idx[i + k] * TD;
            v0[k] = (float)vp[0];
            v1[k] = (float)vp[256];
            v2[k] = (float)vp[512];
            p0[k] = s_p[h0][i + k];
            p1[k] = s_p[h0 + 4][i + k];
            p2[k] = s_p[h0 + 8][i + k];
        }
#pragma unroll
        for (int k = 0; k < 8; ++k) {
            a0 += p0[k] * v0[k];
            a1 += p1[k] * v1[k];
            a2 += p2[k] * v2[k];
        }
    }
    O[(size_t)row * D + t] = (bf16_t)a0;
    O[(size_t)row * D + t + 256] = (bf16_t)a1;
    O[(size_t)row * D + t + 512] = (bf16_t)a2;
}

// ---------- launch ----------
extern "C" void kernel_launch(void* const* d_in, const int* in_sizes, int n_in,
                              void* d_out, int out_size, void* d_ws, size_t ws_size,
                              hipStream_t stream) {
    const float* exp_e = (const float*)d_in[0];
    const float* pert  = (const float*)d_in[1];
    const float* w_in  = (const float*)d_in[2];
    const float* b_in  = (const float*)d_in[3];
    const float* w_out = (const float*)d_in[4];
    const float* b_out = (const float*)d_in[5];
    const float* g0  = (const float*)d_in[6];
    const float* be0 = (const float*)d_in[7];
    const float* g1  = (const float*)d_in[8];
    const float* be1 = (const float*)d_in[9];
    const float* g2  = (const float*)d_in[10];
    const float* be2 = (const float*)d_in[11];
    const float* w1  = (const float*)d_in[12];
    const float* b1  = (const float*)d_in[13];
    const float* w2  = (const float*)d_in[14];
    const float* b2  = (const float*)d_in[15];
    const int*   adj = (const int*)d_in[16];
    float* out = (float*)d_out;

    const size_t SD = (size_t)S * D;
    bf16_t* wb_in  = (bf16_t*)d_ws;               // [2304*768]
    bf16_t* wb_out = wb_in + (size_t)TD * D;      // [768*768]
    bf16_t* wb_1   = wb_out + (size_t)D * D;      // [384*768]
    bf16_t* wb_2   = wb_1 + (size_t)(D / 2) * D;  // [768*384]
    bf16_t* x_in   = wb_2 + (size_t)D * (D / 2);  // [S*D]
    bf16_t* qkv    = x_in + SD;                   // [S*3D]
    bf16_t* attn_o = qkv + 3 * SD;                // [S*D]
    bf16_t* y1     = attn_o + SD;                 // [S*D] pre-LN1
    bf16_t* x1     = y1 + SD;                     // [S*D] ln1 out
    bf16_t* ffh    = x1 + SD;                     // [S*D/2]
    bf16_t* y2     = ffh + SD / 2;                // [S*D] pre-LN2
    int* nbr_idx   = (int*)(y2 + SD);             // [S*128]
    int* nbr_cnt   = nbr_idx + (size_t)S * 128;   // [S]

    addln_cvt<<<ADDLN_B + CVT_B + ADJB_B, 256, 0, stream>>>(exp_e, pert, g0, be0, x_in,
                                                            w_in, w_out, w1, w2, wb_in, wb_out, wb_1, wb_2,
                                                            adj, nbr_idx, nbr_cnt);
    // qkv GEMM: 128x128 tile (proven 128^2 >> 64^2 at identical structure, m92/m103);
    // 288 blocks = ONE co-resident generation (2 blocks/CU x 256 CUs).
    gemm_mfma<128, 128, 0, false><<<dim3(TD / 128, S / 128), 256, 0, stream>>>(x_in, wb_in, b_in, nullptr, qkv, S, TD, D);
    attn_sparse<<<S, 256, 0, stream>>>(qkv, nbr_idx, nbr_cnt, attn_o);
    gemm_mfma<64, 64, 0, true><<<dim3(D / 64, S / 64), 256, 0, stream>>>(attn_o, wb_out, b_out, x_in, y1, S, D, D);
    ln_only<bf16_t><<<S / 4, 256, 0, stream>>>(y1, g1, be1, x1);
    gemm_mfma<32, 64, 1, false><<<dim3((D / 2) / 64, S / 32), 256, 0, stream>>>(x1, wb_1, b1, nullptr, ffh, S, D / 2, D);
    gemm_mfma<64, 64, 0, true><<<dim3(D / 64, S / 64), 256, 0, stream>>>(ffh, wb_2, b2, x1, y2, S, D, D / 2);
    ln_only<float><<<S / 4, 256, 0, stream>>>(y2, g2, be2, out);
}

// Round 17
// 180.344 us; speedup vs baseline: 1.0266x; 1.0174x over previous
//
#include <hip/hip_runtime.h>

#define S 2048
#define D 768
#define NH 12
#define HD 64
#define TD (3 * D)
#define GBK 64

typedef __bf16 bf16_t;
typedef __bf16 v8bf __attribute__((ext_vector_type(8)));
typedef __bf16 v4bf __attribute__((ext_vector_type(4)));
typedef float v4f __attribute__((ext_vector_type(4)));

// ---------- reductions ----------
__device__ __forceinline__ float wave_allreduce_sum(float v) {
#pragma unroll
    for (int o = 32; o > 0; o >>= 1) v += __shfl_xor(v, o, 64);
    return v;
}

// counted vmcnt wait with literal immediates
template <int N>
__device__ __forceinline__ void wait_vmcnt() {
    if constexpr (N == 0) asm volatile("s_waitcnt vmcnt(0)" ::: "memory");
    else if constexpr (N == 1) asm volatile("s_waitcnt vmcnt(1)" ::: "memory");
    else if constexpr (N == 2) asm volatile("s_waitcnt vmcnt(2)" ::: "memory");
    else if constexpr (N == 3) asm volatile("s_waitcnt vmcnt(3)" ::: "memory");
    else if constexpr (N == 4) asm volatile("s_waitcnt vmcnt(4)" ::: "memory");
    else if constexpr (N == 5) asm volatile("s_waitcnt vmcnt(5)" ::: "memory");
    else if constexpr (N == 6) asm volatile("s_waitcnt vmcnt(6)" ::: "memory");
    else if constexpr (N == 7) asm volatile("s_waitcnt vmcnt(7)" ::: "memory");
    else asm volatile("s_waitcnt vmcnt(8)" ::: "memory");
}

// ---------- fused: add+LN (wave-per-row) | weight cvt (4 units/thread) | adj compaction ----------
#define NW0 (TD * D / 4)
#define NW1 (D * D / 4)
#define NW2 ((D / 2) * D / 4)
#define NW3 (D * (D / 2) / 4)
#define NWALL (NW0 + NW1 + NW2 + NW3)
#define ADDLN_B (S / 4)          // 512 blocks, wave-per-row
#define CVT_B 720                // 720 blocks x 1024 units
#define ADJB_B (S / 4)           // 512 blocks, wave-per-row

__global__ __launch_bounds__(256) void addln_cvt(const float* __restrict__ A, const float* __restrict__ Bv,
                                                 const float* __restrict__ g, const float* __restrict__ be,
                                                 bf16_t* __restrict__ out,
                                                 const float* __restrict__ s0, const float* __restrict__ s1,
                                                 const float* __restrict__ s2, const float* __restrict__ s3,
                                                 bf16_t* __restrict__ d0, bf16_t* __restrict__ d1,
                                                 bf16_t* __restrict__ d2, bf16_t* __restrict__ d3,
                                                 const int* __restrict__ adj,
                                                 int* __restrict__ nbr_idx, int* __restrict__ nbr_cnt) {
    const int blk = blockIdx.x, t = threadIdx.x;
    const int lane = t & 63, wave = t >> 6;

    if (blk < ADDLN_B) {
        // add + LN, one wave per row; lane owns 3 float4 chunks (12 elems); no __syncthreads
        const int row = blk * 4 + wave;
        const float4* a4 = (const float4*)(A + (size_t)row * D);
        const float4* b4 = (const float4*)(Bv + (size_t)row * D);
        float4 x[3];
        float s = 0.f;
#pragma unroll
        for (int i = 0; i < 3; ++i) {
            int c = lane + 64 * i;
            float4 av = a4[c], bv = b4[c];
            x[i].x = av.x + bv.x; x[i].y = av.y + bv.y;
            x[i].z = av.z + bv.z; x[i].w = av.w + bv.w;
            s += x[i].x + x[i].y + x[i].z + x[i].w;
        }
        float mean = wave_allreduce_sum(s) * (1.0f / D);
        float vs = 0.f;
#pragma unroll
        for (int i = 0; i < 3; ++i) {
            float dx = x[i].x - mean, dy = x[i].y - mean, dz = x[i].z - mean, dw = x[i].w - mean;
            vs += dx * dx + dy * dy + dz * dz + dw * dw;
        }
        float rstd = rsqrtf(wave_allreduce_sum(vs) * (1.0f / D) + 1e-5f);
#pragma unroll
        for (int i = 0; i < 3; ++i) {
            int c = lane + 64 * i;
            float4 gv = ((const float4*)g)[c];
            float4 bev = ((const float4*)be)[c];
            v4bf o = {(bf16_t)((x[i].x - mean) * rstd * gv.x + bev.x),
                      (bf16_t)((x[i].y - mean) * rstd * gv.y + bev.y),
                      (bf16_t)((x[i].z - mean) * rstd * gv.z + bev.z),
                      (bf16_t)((x[i].w - mean) * rstd * gv.w + bev.w)};
            *(v4bf*)(out + (size_t)row * D + c * 4) = o;
        }
        return;
    }
    if (blk < ADDLN_B + CVT_B) {
        // weight conversion: 4 float4 units per thread
        int base = (blk - ADDLN_B) * 1024 + t;
#pragma unroll
        for (int r = 0; r < 4; ++r) {
            int i = base + 256 * r;
            if (i >= NWALL) break;
            const float* sp; bf16_t* dp;
            if (i < NW0) { sp = s0; dp = d0; }
            else if (i < NW0 + NW1) { sp = s1; dp = d1; i -= NW0; }
            else if (i < NW0 + NW1 + NW2) { sp = s2; dp = d2; i -= NW0 + NW1; }
            else { sp = s3; dp = d3; i -= NW0 + NW1 + NW2; }
            float4 v = ((const float4*)sp)[i];
            v4bf o = {(bf16_t)v.x, (bf16_t)v.y, (bf16_t)v.z, (bf16_t)v.w};
            *(v4bf*)(dp + (size_t)i * 4) = o;
        }
        return;
    }
    // adjacency compaction: wave-per-row ballot scan (deterministic; R3-verified)
    {
        const int row = (blk - ADDLN_B - CVT_B) * 4 + wave;
        int cnt = 0;
        const int4* arow = (const int4*)(adj + (size_t)row * S);
        const unsigned long long lt = (1ull << lane) - 1;
        int* dst = nbr_idx + (size_t)row * 128;
#pragma unroll
        for (int p = 0; p < 8; ++p) {
            int4 v = arow[lane + 64 * p];
            int base = (lane + 64 * p) * 4;
            int f[4] = {v.x, v.y, v.z, v.w};
#pragma unroll
            for (int c = 0; c < 4; ++c) {
                unsigned long long m = __ballot(f[c] != 0);
                if (f[c]) {
                    int k = cnt + (int)__popcll(m & lt);
                    if (k < 128) dst[k] = base + c;
                }
                cnt += (int)__popcll(m);
            }
        }
        if (lane == 0) nbr_cnt[row] = (cnt < 128) ? cnt : 128;
    }
}

// ---------- single-input LayerNorm: wave-per-row, 4 rows/block, no __syncthreads ----------
template <typename TO>
__global__ __launch_bounds__(256) void ln_only(const bf16_t* __restrict__ X,
                                               const float* __restrict__ g, const float* __restrict__ be,
                                               TO* __restrict__ out) {
    const int lane = threadIdx.x & 63, wave = threadIdx.x >> 6;
    const int row = blockIdx.x * 4 + wave;
    const bf16_t* a = X + (size_t)row * D;

    // lane owns v8bf chunk `lane`; lanes 0..31 additionally own chunk lane+64 (96 chunks total)
    float xa[8], xb[8];
    float s = 0.f;
    v8bf ya = *(const v8bf*)(a + lane * 8);
#pragma unroll
    for (int e = 0; e < 8; ++e) { xa[e] = (float)ya[e]; s += xa[e]; }
    if (lane < 32) {
        v8bf yb = *(const v8bf*)(a + (lane + 64) * 8);
#pragma unroll
        for (int e = 0; e < 8; ++e) { xb[e] = (float)yb[e]; s += xb[e]; }
    }
    float mean = wave_allreduce_sum(s) * (1.0f / D);
    float vs = 0.f;
#pragma unroll
    for (int e = 0; e < 8; ++e) { float d2 = xa[e] - mean; vs += d2 * d2; }
    if (lane < 32) {
#pragma unroll
        for (int e = 0; e < 8; ++e) { float d2 = xb[e] - mean; vs += d2 * d2; }
    }
    float rstd = rsqrtf(wave_allreduce_sum(vs) * (1.0f / D) + 1e-5f);

    {
        float4 g0 = *(const float4*)(g + lane * 8), g1 = *(const float4*)(g + lane * 8 + 4);
        float4 b0 = *(const float4*)(be + lane * 8), b1 = *(const float4*)(be + lane * 8 + 4);
        float r0[8] = {g0.x, g0.y, g0.z, g0.w, g1.x, g1.y, g1.z, g1.w};
        float r1[8] = {b0.x, b0.y, b0.z, b0.w, b1.x, b1.y, b1.z, b1.w};
        if constexpr (sizeof(TO) == 2) {
            v8bf o;
#pragma unroll
            for (int e = 0; e < 8; ++e) o[e] = (bf16_t)((xa[e] - mean) * rstd * r0[e] + r1[e]);
            *(v8bf*)((bf16_t*)out + (size_t)row * D + lane * 8) = o;
        } else {
            float4 o0, o1;
            o0.x = (xa[0] - mean) * rstd * r0[0] + r1[0]; o0.y = (xa[1] - mean) * rstd * r0[1] + r1[1];
            o0.z = (xa[2] - mean) * rstd * r0[2] + r1[2]; o0.w = (xa[3] - mean) * rstd * r0[3] + r1[3];
            o1.x = (xa[4] - mean) * rstd * r0[4] + r1[4]; o1.y = (xa[5] - mean) * rstd * r0[5] + r1[5];
            o1.z = (xa[6] - mean) * rstd * r0[6] + r1[6]; o1.w = (xa[7] - mean) * rstd * r0[7] + r1[7];
            *(float4*)((float*)out + (size_t)row * D + lane * 8) = o0;
            *(float4*)((float*)out + (size_t)row * D + lane * 8 + 4) = o1;
        }
    }
    if (lane < 32) {
        const int c0 = (lane + 64) * 8;
        float4 g0 = *(const float4*)(g + c0), g1 = *(const float4*)(g + c0 + 4);
        float4 b0 = *(const float4*)(be + c0), b1 = *(const float4*)(be + c0 + 4);
        float r0[8] = {g0.x, g0.y, g0.z, g0.w, g1.x, g1.y, g1.z, g1.w};
        float r1[8] = {b0.x, b0.y, b0.z, b0.w, b1.x, b1.y, b1.z, b1.w};
        if constexpr (sizeof(TO) == 2) {
            v8bf o;
#pragma unroll
            for (int e = 0; e < 8; ++e) o[e] = (bf16_t)((xb[e] - mean) * rstd * r0[e] + r1[e]);
            *(v8bf*)((bf16_t*)out + (size_t)row * D + c0) = o;
        } else {
            float4 o0, o1;
            o0.x = (xb[0] - mean) * rstd * r0[0] + r1[0]; o0.y = (xb[1] - mean) * rstd * r0[1] + r1[1];
            o0.z = (xb[2] - mean) * rstd * r0[2] + r1[2]; o0.w = (xb[3] - mean) * rstd * r0[3] + r1[3];
            o1.x = (xb[4] - mean) * rstd * r0[4] + r1[4]; o1.y = (xb[5] - mean) * rstd * r0[5] + r1[5];
            o1.z = (xb[6] - mean) * rstd * r0[6] + r1[6]; o1.w = (xb[7] - mean) * rstd * r0[7] + r1[7];
            *(float4*)((float*)out + (size_t)row * D + c0) = o0;
            *(float4*)((float*)out + (size_t)row * D + c0 + 4) = o1;
        }
    }
}

// ---------- MFMA GEMM (R1-proven dbuf + counted vmcnt) ----------
template <int TM, int TN, int RELU, bool RESID>
__global__ __launch_bounds__(256) void gemm_mfma(const bf16_t* __restrict__ A, const bf16_t* __restrict__ B,
                                                 const float* __restrict__ bias,
                                                 const bf16_t* __restrict__ Rsd, bf16_t* __restrict__ C,
                                                 int M, int N, int K) {
    constexpr int CA = TM * 8;
    constexpr int CHUNKS = (TM + TN) * 8;
    constexpr int P = CHUNKS / 256;
    static_assert(CHUNKS % 256 == 0, "chunk passes must be exact");
    constexpr int MI = TM / 32, NI = TN / 32;
    constexpr int BUFE = (TM + TN) * GBK;
    __shared__ bf16_t smem[2 * BUFE];
    const int t = threadIdx.x;
    const int lane = t & 63, wave = t >> 6;
    const int wr = (wave >> 1) * (TM / 2), wc = (wave & 1) * (TN / 2);
    const int m0 = blockIdx.y * TM, n0 = blockIdx.x * TN;
    const int lm = lane & 15, q = lane >> 4;

    const bf16_t* gp[P];
    int loff[P];
#pragma unroll
    for (int p = 0; p < P; ++p) {
        int c = t + 256 * p;
        if (c < CA) {
            int slab = c / (TM * 4), r4 = c % (TM * 4);
            gp[p] = A + (size_t)(m0 + (r4 >> 2)) * K + slab * 32 + (r4 & 3) * 8;
            loff[p] = slab * (TM * 32) + r4 * 8;
        } else {
            int cc = c - CA;
            int slab = cc / (TN * 4), r4 = cc % (TN * 4);
            gp[p] = B + (size_t)(n0 + (r4 >> 2)) * K + slab * 32 + (r4 & 3) * 8;
            loff[p] = TM * GBK + slab * (TN * 32) + r4 * 8;
        }
    }

    v4f acc[MI][NI] = {};

    auto stage = [&](int buf, int k0) {
#pragma unroll
        for (int p = 0; p < P; ++p)
            __builtin_amdgcn_global_load_lds(
                (const __attribute__((address_space(1))) void*)(gp[p] + k0),
                (__attribute__((address_space(3))) void*)(smem + buf * BUFE + loff[p]), 16, 0, 0);
    };

    stage(0, 0);
    int cur = 0;
    for (int k0 = 0; k0 < K; k0 += GBK) {
        if (k0 + GBK < K) {
            stage(cur ^ 1, k0 + GBK);
            __builtin_amdgcn_sched_barrier(0);
            wait_vmcnt<P>();
        } else {
            __builtin_amdgcn_sched_barrier(0);
            wait_vmcnt<0>();
        }
        __builtin_amdgcn_s_barrier();
        __builtin_amdgcn_sched_barrier(0);

        const bf16_t* As = smem + cur * BUFE;
        const bf16_t* Bs = As + TM * GBK;
        v8bf af[2][MI], bfr[2][NI];
#pragma unroll
        for (int s = 0; s < 2; ++s) {
#pragma unroll
            for (int i = 0; i < MI; ++i)
                af[s][i] = *(const v8bf*)(As + s * (TM * 32) + (wr + i * 16 + lm) * 32 + q * 8);
#pragma unroll
            for (int j = 0; j < NI; ++j)
                bfr[s][j] = *(const v8bf*)(Bs + s * (TN * 32) + (wc + j * 16 + lm) * 32 + q * 8);
        }
#pragma unroll
        for (int s = 0; s < 2; ++s)
#pragma unroll
            for (int i = 0; i < MI; ++i)
#pragma unroll
                for (int j = 0; j < NI; ++j)
                    acc[i][j] = __builtin_amdgcn_mfma_f32_16x16x32_bf16(af[s][i], bfr[s][j], acc[i][j], 0, 0, 0);
        __builtin_amdgcn_sched_barrier(0);
        __builtin_amdgcn_s_barrier();
        cur ^= 1;
    }

    // D mapping (verified m89/m91): row = quad*4 + reg, col = lane&15
#pragma unroll
    for (int i = 0; i < MI; ++i)
#pragma unroll
        for (int j = 0; j < NI; ++j) {
            int col = n0 + wc + j * 16 + lm;
            float bs = bias[col];
#pragma unroll
            for (int r = 0; r < 4; ++r) {
                int row = m0 + wr + i * 16 + q * 4 + r;
                float v = acc[i][j][r] + bs;
                if (RELU) v = fmaxf(v, 0.f);
                if (RESID) v += (float)Rsd[(size_t)row * N + col];
                C[(size_t)row * N + col] = (bf16_t)v;
            }
        }
}

// ---------- sparse attention (R7-proven: thread-per-dot scores + fused PV) ----------
__global__ __launch_bounds__(256) void attn_sparse(const bf16_t* __restrict__ qkv,
                                                   const int* __restrict__ nbr_idx,
                                                   const int* __restrict__ nbr_cnt,
                                                   bf16_t* __restrict__ O) {
    __shared__ int s_idx[128];
    __shared__ float s_q[D];
    __shared__ float s_p[NH][128];

    const int row = blockIdx.x, t = threadIdx.x;
    const int lane = t & 63, wave = t >> 6;
    const int n = nbr_cnt[row];           // >= 1 (diag forced), <= 128
    const int npad = (n + 7) & ~7;        // pad to x8; pads get p=0 (exact no-op)

    if (t < 128) s_idx[t] = (t < n) ? nbr_idx[(size_t)row * 128 + t] : row;
    for (int c = t; c < D; c += 256) s_q[c] = (float)qkv[(size_t)row * TD + c];
    __syncthreads();

    // scores over padded range; pad entries written 0 and untouched by softmax
    for (int it = t; it < npad * NH; it += 256) {
        int h = it / npad, i = it - h * npad;
        if (i < n) {
            int j = s_idx[i];
            const bf16_t* kp = qkv + (size_t)j * TD + D + h * HD;
            const float* qp = s_q + h * HD;
            float dot = 0.f;
#pragma unroll
            for (int c = 0; c < HD; c += 8) {
                v8bf kv = *(const v8bf*)(kp + c);
#pragma unroll
                for (int e = 0; e < 8; ++e) dot += qp[c + e] * (float)kv[e];
            }
            s_p[h][i] = dot * 0.125f;  // 1/sqrt(64)
        } else {
            s_p[h][i] = 0.f;
        }
    }
    __syncthreads();

    // softmax: 3 heads per wave (reads/writes only i < n)
    for (int h = wave; h < NH; h += 4) {
        float v0 = (lane < n) ? s_p[h][lane] : -1e30f;
        float v1 = (lane + 64 < n) ? s_p[h][lane + 64] : -1e30f;
        float m = fmaxf(v0, v1);
#pragma unroll
        for (int o = 32; o > 0; o >>= 1) m = fmaxf(m, __shfl_xor(m, o, 64));
        float p0 = (lane < n) ? __expf(v0 - m) : 0.f;
        float p1 = (lane + 64 < n) ? __expf(v1 - m) : 0.f;
        float sm = p0 + p1;
#pragma unroll
        for (int o = 32; o > 0; o >>= 1) sm += __shfl_xor(sm, o, 64);
        float inv = 1.f / sm;
        if (lane < n) s_p[h][lane] = p0 * inv;
        if (lane + 64 < n) s_p[h][lane + 64] = p1 * inv;
    }
    __syncthreads();

    // PV: thread owns outputs {t, t+256, t+512} = heads {h0, h0+4, h0+8}, elem e.
    const int h0 = t >> 6, e = t & 63;
    const bf16_t* vbase = qkv + 2 * D + h0 * HD + e;
    float a0 = 0.f, a1 = 0.f, a2 = 0.f;
    for (int i = 0; i < npad; i += 8) {
        float v0[8], v1[8], v2[8], p0[8], p1[8], p2[8];
#pragma unroll
        for (int k = 0; k < 8; ++k) {
            const bf16_t* vp = vbase + (size_t)s_idx[i + k] * TD;
            v0[k] = (float)vp[0];
            v1[k] = (float)vp[256];
            v2[k] = (float)vp[512];
            p0[k] = s_p[h0][i + k];
            p1[k] = s_p[h0 + 4][i + k];
            p2[k] = s_p[h0 + 8][i + k];
        }
#pragma unroll
        for (int k = 0; k < 8; ++k) {
            a0 += p0[k] * v0[k];
            a1 += p1[k] * v1[k];
            a2 += p2[k] * v2[k];
        }
    }
    O[(size_t)row * D + t] = (bf16_t)a0;
    O[(size_t)row * D + t + 256] = (bf16_t)a1;
    O[(size_t)row * D + t + 512] = (bf16_t)a2;
}

// ---------- launch ----------
extern "C" void kernel_launch(void* const* d_in, const int* in_sizes, int n_in,
                              void* d_out, int out_size, void* d_ws, size_t ws_size,
                              hipStream_t stream) {
    const float* exp_e = (const float*)d_in[0];
    const float* pert  = (const float*)d_in[1];
    const float* w_in  = (const float*)d_in[2];
    const float* b_in  = (const float*)d_in[3];
    const float* w_out = (const float*)d_in[4];
    const float* b_out = (const float*)d_in[5];
    const float* g0  = (const float*)d_in[6];
    const float* be0 = (const float*)d_in[7];
    const float* g1  = (const float*)d_in[8];
    const float* be1 = (const float*)d_in[9];
    const float* g2  = (const float*)d_in[10];
    const float* be2 = (const float*)d_in[11];
    const float* w1  = (const float*)d_in[12];
    const float* b1  = (const float*)d_in[13];
    const float* w2  = (const float*)d_in[14];
    const float* b2  = (const float*)d_in[15];
    const int*   adj = (const int*)d_in[16];
    float* out = (float*)d_out;

    const size_t SD = (size_t)S * D;
    bf16_t* wb_in  = (bf16_t*)d_ws;               // [2304*768]
    bf16_t* wb_out = wb_in + (size_t)TD * D;      // [768*768]
    bf16_t* wb_1   = wb_out + (size_t)D * D;      // [384*768]
    bf16_t* wb_2   = wb_1 + (size_t)(D / 2) * D;  // [768*384]
    bf16_t* x_in   = wb_2 + (size_t)D * (D / 2);  // [S*D]
    bf16_t* qkv    = x_in + SD;                   // [S*3D]
    bf16_t* attn_o = qkv + 3 * SD;                // [S*D]
    bf16_t* y1     = attn_o + SD;                 // [S*D] pre-LN1
    bf16_t* x1     = y1 + SD;                     // [S*D] ln1 out
    bf16_t* ffh    = x1 + SD;                     // [S*D/2]
    bf16_t* y2     = ffh + SD / 2;                // [S*D] pre-LN2
    int* nbr_idx   = (int*)(y2 + SD);             // [S*128]
    int* nbr_cnt   = nbr_idx + (size_t)S * 128;   // [S]

    addln_cvt<<<ADDLN_B + CVT_B + ADJB_B, 256, 0, stream>>>(exp_e, pert, g0, be0, x_in,
                                                            w_in, w_out, w1, w2, wb_in, wb_out, wb_1, wb_2,
                                                            adj, nbr_idx, nbr_cnt);
    gemm_mfma<64, 128, 0, false><<<dim3(TD / 128, S / 64), 256, 0, stream>>>(x_in, wb_in, b_in, nullptr, qkv, S, TD, D);
    attn_sparse<<<S, 256, 0, stream>>>(qkv, nbr_idx, nbr_cnt, attn_o);
    gemm_mfma<64, 64, 0, true><<<dim3(D / 64, S / 64), 256, 0, stream>>>(attn_o, wb_out, b_out, x_in, y1, S, D, D);
    ln_only<bf16_t><<<S / 4, 256, 0, stream>>>(y1, g1, be1, x1);
    gemm_mfma<32, 64, 1, false><<<dim3((D / 2) / 64, S / 32), 256, 0, stream>>>(x1, wb_1, b1, nullptr, ffh, S, D / 2, D);
    gemm_mfma<64, 64, 0, true><<<dim3(D / 64, S / 64), 256, 0, stream>>>(ffh, wb_2, b2, x1, y2, S, D, D / 2);
    ln_only<float><<<S / 4, 256, 0, stream>>>(y2, g2, be2, out);
}